// Round 15
// baseline (60.496 us; speedup 1.0000x reference)
//
#include <hip/hip_runtime.h>

#define BB 4
#define NN 8192
#define THREADS 256
#define CPB 1024               // cols per block, staged once
#define TPW (CPB / 32)         // 32 col-tiles per wave

typedef float f32x16 __attribute__((ext_vector_type(16)));
typedef __bf16 bf16x8 __attribute__((ext_vector_type(8)));

// ws layout:
//   [0, 128K)   : min1[32768] (uint bits of d^2)
//   [128K,256K) : min2[32768]
//   [256K, ...) : 8 vec planes of 32768 uint4 (512KB each):
//                 (role r: 0=gtA, 1=predA, 2=gtB, 3=predB) x (half h: 0,1)
#define VOFF (1u << 18)

__device__ inline float max3f(float a, float b, float c) {
    float d;
    asm("v_max3_f32 %0, %1, %2, %3" : "=v"(d) : "v"(a), "v"(b), "v"(c));
    return d;
}

__device__ inline unsigned short brne(float x) {   // fp32 -> bf16 RNE bits
    unsigned u = __float_as_uint(x);
    return (unsigned short)((u + 0x7FFFu + ((u >> 16) & 1)) >> 16);
}
__device__ inline unsigned pk(unsigned a, unsigned b) { return a | (b << 16); }

__device__ inline const uint4* vplane(const unsigned* ws, int r, int h) {
    return (const uint4*)((const char*)ws + VOFF + (((unsigned)(r * 2 + h)) << 19));
}

// 131072 threads: tid = role(4) x batch(4) x n(8192). Also inits mins.
__global__ __launch_bounds__(256) void cd_pre_kernel(
    const float* __restrict__ pred, const float* __restrict__ gt,
    const float* __restrict__ coords, unsigned int* __restrict__ ws)
{
    int tid = blockIdx.x * 256 + threadIdx.x;
    if (tid < 65536) ws[tid] = 0x7F800000u;   // min1/min2 = +inf

    int r = tid >> 15;            // 0 gtA, 1 predA, 2 gtB, 3 predB
    int b = (tid >> 13) & 3;
    int n = tid & 8191;
    const float* sb = ((r & 1) ? pred : gt) + b * 3 * NN;
    const float* cb = coords + b * 3 * NN;
    float x = cb[0 * NN + n] + sb[0 * NN + n];
    float y = cb[1 * NN + n] + sb[1 * NN + n];
    float z = cb[2 * NN + n] + sb[2 * NN + n];
    float w = -0.5f * fmaf(x, x, fmaf(y, y, z * z));

    unsigned short hx = brne(x); unsigned short lx = brne(x - __uint_as_float((unsigned)hx << 16));
    unsigned short hy = brne(y); unsigned short ly = brne(y - __uint_as_float((unsigned)hy << 16));
    unsigned short hz = brne(z); unsigned short lz = brne(z - __uint_as_float((unsigned)hz << 16));
    unsigned short hw = brne(w); unsigned short lw = brne(w - __uint_as_float((unsigned)hw << 16));
    const unsigned short ONE = 0x3F80;

    uint4 h0, h1;
    if (r < 2) {       // A slots: hx hy hz lx ly lz hx hy | hz hw lw 1 1 0 0 0
        h0 = make_uint4(pk(hx, hy), pk(hz, lx), pk(ly, lz), pk(hx, hy));
        h1 = make_uint4(pk(hz, hw), pk(lw, ONE), pk(ONE, 0), 0u);
    } else {           // B slots: hx hy hz hx hy hz lx ly | lz 1 1 hw lw 0 0 0
        h0 = make_uint4(pk(hx, hy), pk(hz, hx), pk(hy, hz), pk(lx, ly));
        h1 = make_uint4(pk(lz, ONE), pk(ONE, hw), pk(lw, 0), 0u);
    }
    unsigned idx = (unsigned)(b * 8192 + n);
    ((uint4*)((char*)ws + VOFF + (((unsigned)(r * 2 + 0)) << 19)))[idx] = h0;
    ((uint4*)((char*)ws + VOFF + (((unsigned)(r * 2 + 1)) << 19)))[idx] = h1;
}

// grid 4096: (cq 8) x (pb 64) x (b 4) x (dir 2)
// block = 4 waves x 32 rows = 128 rows, scans 1024 cols staged ONCE in LDS.
__global__ __launch_bounds__(THREADS) void cd_mfma_kernel(unsigned int* ws)
{
    __shared__ uint4 colv[2 * CPB];   // [half*CPB + col], 32 KB

    int bid = blockIdx.x;
    int cq  = bid & 7;
    int pb  = (bid >> 3) & 63;
    int b   = (bid >> 9) & 3;
    int dir = bid >> 11;

    int tid  = threadIdx.x;
    int w    = tid >> 6;
    int lane = tid & 63;
    int cl   = lane & 31;
    int hi   = lane >> 5;

    // dir0: rows=gt(A,r0) vs cols=pred(B,r3) -> min1 ; dir1: rows=pred(A,r1) vs cols=gt(B,r2) -> min2
    const uint4* Ah = vplane(ws, dir ? 1 : 0, hi);
    const uint4* B0 = vplane(ws, dir ? 2 : 3, 0);
    const uint4* B1 = vplane(ws, dir ? 2 : 3, 1);

    int arow = b * 8192 + pb * 128 + w * 32 + cl;
    bf16x8 afrag = __builtin_bit_cast(bf16x8, Ah[arow]);

    // stage 1024 cols x 2 halves (plain ds_write, verified pattern)
    int colbase = b * 8192 + cq * CPB;
#pragma unroll
    for (int i = 0; i < CPB / THREADS; i++) {
        colv[tid + i * THREADS]       = B0[colbase + tid + i * THREADS];
        colv[CPB + tid + i * THREADS] = B1[colbase + tid + i * THREADS];
    }
    __syncthreads();

    f32x16 zacc{};
    float rm[16];
#pragma unroll
    for (int j = 0; j < 16; j++) rm[j] = -3.0e38f;

    const uint4* lbase = &colv[hi * CPB + cl];
#pragma unroll 4
    for (int p = 0; p < TPW / 2; p++) {       // 16 pairs of col-tiles
        bf16x8 bfA = __builtin_bit_cast(bf16x8, lbase[(2 * p) * 32]);
        bf16x8 bfB = __builtin_bit_cast(bf16x8, lbase[(2 * p + 1) * 32]);
        f32x16 dA = __builtin_amdgcn_mfma_f32_32x32x16_bf16(afrag, bfA, zacc, 0, 0, 0);
        f32x16 dB = __builtin_amdgcn_mfma_f32_32x32x16_bf16(afrag, bfB, zacc, 0, 0, 0);
#pragma unroll
        for (int j = 0; j < 16; j++) rm[j] = max3f(rm[j], dA[j], dB[j]);
    }

    // fold rm across the 32 cl-lanes (row identity depends only on (w,hi,j))
#pragma unroll
    for (int j = 0; j < 16; j++) {
        float v = rm[j];
        v = fmaxf(v, __shfl_xor(v, 1, 64));
        v = fmaxf(v, __shfl_xor(v, 2, 64));
        v = fmaxf(v, __shfl_xor(v, 4, 64));
        v = fmaxf(v, __shfl_xor(v, 8, 64));
        v = fmaxf(v, __shfl_xor(v, 16, 64));
        rm[j] = v;
    }
    if (cl == 0) {
        unsigned int* minout = ws + (dir ? 32768 : 0);
#pragma unroll
        for (int j = 0; j < 16; j++) {
            int row = pb * 128 + w * 32 + (j & 3) + 8 * (j >> 2) + 4 * hi;
            float d2 = fmaxf(-2.0f * rm[j], 0.0f);
            atomicMin(&minout[b * 8192 + row], __float_as_uint(d2));
        }
    }
}

__global__ __launch_bounds__(1024) void cd_reduce_kernel(const unsigned int* __restrict__ mins,
                                                         float* __restrict__ out)
{
    float s = 0.0f;
#pragma unroll
    for (int k = 0; k < 2 * BB * NN / 1024; ++k)
        s += __uint_as_float(mins[threadIdx.x + k * 1024]);
#pragma unroll
    for (int off = 32; off > 0; off >>= 1)
        s += __shfl_down(s, off, 64);
    __shared__ float wsum[16];
    int wave = threadIdx.x >> 6;
    if ((threadIdx.x & 63) == 0) wsum[wave] = s;
    __syncthreads();
    if (threadIdx.x == 0) {
        float t = 0.0f;
#pragma unroll
        for (int v = 0; v < 16; ++v) t += wsum[v];
        out[0] = t / (float)BB;
    }
}

extern "C" void kernel_launch(void* const* d_in, const int* in_sizes, int n_in,
                              void* d_out, int out_size, void* d_ws, size_t ws_size,
                              hipStream_t stream) {
    const float* pred   = (const float*)d_in[0];
    const float* gt     = (const float*)d_in[1];
    const float* coords = (const float*)d_in[2];
    float* out = (float*)d_out;
    unsigned int* ws = (unsigned int*)d_ws;

    hipLaunchKernelGGL(cd_pre_kernel, dim3(512), dim3(256), 0, stream,
                       pred, gt, coords, ws);
    hipLaunchKernelGGL(cd_mfma_kernel, dim3(4096), dim3(256), 0, stream, ws);
    hipLaunchKernelGGL(cd_reduce_kernel, dim3(1), dim3(1024), 0, stream, ws, out);
}

// Round 16
// 57.877 us; speedup vs baseline: 1.0453x; 1.0453x over previous
//
#include <hip/hip_runtime.h>

#define BB 4
#define NN 8192
#define RI 16                  // rows per thread
#define THREADS 256
#define ROWB (THREADS * RI)    // 4096 rows per block
#define PB (NN / ROWB)         // 2 row-panels
#define COLB 64                // cols per block (staged once)
#define NCB (NN / COLB)        // 128 col-blocks

__device__ inline float max3f(float a, float b, float c) {
    float d;
    asm("v_max3_f32 %0, %1, %2, %3" : "=v"(d) : "v"(a), "v"(b), "v"(c));
    return d;
}

__global__ void cd_init_kernel(unsigned int* mins, int n) {
    int i = blockIdx.x * blockDim.x + threadIdx.x;
    if (i < n) mins[i] = 0x7F800000u;  // +inf
}

// u = p.q - 0.5|p|^2 - 0.5|q|^2 = -0.5 d^2 <= 0.
// rm folds t = p.q + wq over cols (wp added back in row epilogue).
// col-min d^2 <-> col-max u (LDS ds_min on bit patterns).
// float-max over non-positive floats == uint-min over bit patterns (exact).
__global__ __launch_bounds__(THREADS) void cd_both_kernel(
    const float* __restrict__ pred, const float* __restrict__ gt,
    const float* __restrict__ coords,
    unsigned int* __restrict__ min1, unsigned int* __restrict__ min2)
{
    __shared__ float4 s4[COLB];           // (x, y, z, wq=-0.5|q|^2)
    __shared__ unsigned int colm[COLB];   // bits of col-max u

    int bid = blockIdx.x;
    int cb  = bid & (NCB - 1);
    int pb  = (bid >> 7) & (PB - 1);
    int b   = bid >> 8;

    const float* cbase = coords + b * 3 * NN;
    const float* gbase = gt   + b * 3 * NN;   // rows: gt  -> min1
    const float* pbase = pred + b * 3 * NN;   // cols: gen -> min2

    int tid  = threadIdx.x;
    int lane = tid & 63;

    // stage 64 cols + init colm (one barrier)
    if (tid < COLB) {
        int n = cb * COLB + tid;
        float x = cbase[0 * NN + n] + pbase[0 * NN + n];
        float y = cbase[1 * NN + n] + pbase[1 * NN + n];
        float z = cbase[2 * NN + n] + pbase[2 * NN + n];
        float w = -0.5f * fmaf(x, x, fmaf(y, y, z * z));
        s4[tid] = make_float4(x, y, z, w);
        colm[tid] = 0xFF800000u;  // -inf bits (umin identity)
    }

    // 16 rows into registers (fully unrolled -> static indices, stays in VGPRs)
    int r0 = pb * ROWB;
    float px[RI], py[RI], pz[RI], wp[RI], rm[RI];
#pragma unroll
    for (int i = 0; i < RI; i++) {
        int n = r0 + tid + i * THREADS;
        float x = cbase[0 * NN + n] + gbase[0 * NN + n];
        float y = cbase[1 * NN + n] + gbase[1 * NN + n];
        float z = cbase[2 * NN + n] + gbase[2 * NN + n];
        px[i] = x; py[i] = y; pz[i] = z;
        wp[i] = -0.5f * fmaf(x, x, fmaf(y, y, z * z));
        rm[i] = -3.0e38f;
    }

    __syncthreads();

    // 64 cols, lane-staggered, 1-ahead prefetch
    float4 q = s4[lane];
#pragma unroll 4
    for (int k = 0; k < COLB; ++k) {
        int c  = (lane + k) & (COLB - 1);
        float4 qn = s4[(lane + k + 1) & (COLB - 1)];   // prefetch (last wraps, harmless)

        float t[RI];
#pragma unroll
        for (int i = 0; i < RI; i++) t[i] = fmaf(px[i], q.x, q.w);
#pragma unroll
        for (int i = 0; i < RI; i++) t[i] = fmaf(py[i], q.y, t[i]);
#pragma unroll
        for (int i = 0; i < RI; i++) t[i] = fmaf(pz[i], q.z, t[i]);
#pragma unroll
        for (int i = 0; i < RI; i++) rm[i] = fmaxf(rm[i], t[i]);
        // col fold: u_i = t_i + wp_i ; tree-max 16 -> 1 ; one ds_min
#pragma unroll
        for (int i = 0; i < RI; i++) t[i] += wp[i];
        float a0 = max3f(t[0],  t[1],  t[2]);
        float a1 = max3f(t[3],  t[4],  t[5]);
        float a2 = max3f(t[6],  t[7],  t[8]);
        float a3 = max3f(t[9],  t[10], t[11]);
        float a4 = max3f(t[12], t[13], t[14]);
        float b0 = max3f(a0, a1, t[15]);
        float b1 = max3f(a2, a3, a4);
        float cf = fmaxf(b0, b1);
        atomicMin(&colm[c], __float_as_uint(cf));

        q = qn;
    }

    // row epilogue: max u = rm + wp ; d^2 = -2*(rm+wp), clamp >= 0
#pragma unroll
    for (int i = 0; i < RI; i++) {
        float d = fmaxf(-2.0f * (rm[i] + wp[i]), 0.0f);
        int n = r0 + tid + i * THREADS;
        atomicMin(&min1[b * NN + n], __float_as_uint(d));
    }

    __syncthreads();   // drain ds_min before reading colm
    if (tid < COLB) {
        float u = __uint_as_float(colm[tid]);
        float d = fmaxf(-2.0f * u, 0.0f);
        atomicMin(&min2[b * NN + cb * COLB + tid], __float_as_uint(d));
    }
}

__global__ __launch_bounds__(1024) void cd_reduce_kernel(const unsigned int* __restrict__ mins,
                                                         float* __restrict__ out)
{
    float s = 0.0f;
#pragma unroll
    for (int k = 0; k < 2 * BB * NN / 1024; ++k)
        s += __uint_as_float(mins[threadIdx.x + k * 1024]);
#pragma unroll
    for (int off = 32; off > 0; off >>= 1)
        s += __shfl_down(s, off, 64);
    __shared__ float wsum[16];
    int wave = threadIdx.x >> 6;
    if ((threadIdx.x & 63) == 0) wsum[wave] = s;
    __syncthreads();
    if (threadIdx.x == 0) {
        float t = 0.0f;
#pragma unroll
        for (int w = 0; w < 16; ++w) t += wsum[w];
        out[0] = t / (float)BB;
    }
}

extern "C" void kernel_launch(void* const* d_in, const int* in_sizes, int n_in,
                              void* d_out, int out_size, void* d_ws, size_t ws_size,
                              hipStream_t stream) {
    const float* pred   = (const float*)d_in[0];
    const float* gt     = (const float*)d_in[1];
    const float* coords = (const float*)d_in[2];
    float* out = (float*)d_out;

    unsigned int* mins = (unsigned int*)d_ws;       // min1[BB*NN] then min2[BB*NN]
    unsigned int* min1 = mins;
    unsigned int* min2 = mins + BB * NN;

    int total_mins = 2 * BB * NN;                   // 65536
    hipLaunchKernelGGL(cd_init_kernel, dim3(total_mins / 256), dim3(256), 0, stream,
                       mins, total_mins);

    int nblocks = PB * NCB * BB;                    // 1024
    hipLaunchKernelGGL(cd_both_kernel, dim3(nblocks), dim3(THREADS), 0, stream,
                       pred, gt, coords, min1, min2);

    hipLaunchKernelGGL(cd_reduce_kernel, dim3(1), dim3(1024), 0, stream, mins, out);
}